// Round 13
// baseline (202.490 us; speedup 1.0000x reference)
//
#include <hip/hip_runtime.h>

#define EPSF 1e-10f

constexpr unsigned KEY15 = 0xBFC00000u;  // f2key(1.5f), bucket-aligned
constexpr int BUCK0 = 0xBFC;             // first tracked bucket (3068)
constexpr int NB2   = 4096 - BUCK0;      // 1028 tracked buckets
constexpr int NBKT  = 4096;
constexpr int NREP  = 8;                 // replica rows for flush
constexpr int TPB   = 4;                 // tiles (8192 elems) per block

typedef float pf4 __attribute__((ext_vector_type(4)));
typedef int   pi4 __attribute__((ext_vector_type(4)));

// ---------- workspace layout (words) ----------
// sc: 0 np(u32) 1 psig(f32) 2 plos(f32) 3 k(u32) 7 flag(u32)
constexpr int SC_OFF    = 0;
constexpr int BSTAT_OFF = 64;                       // 4096 float4 (16384 words)
constexpr int REP_OFF   = BSTAT_OFF + 4096 * 4;     // 16448
constexpr int LOW_OFF   = REP_OFF + NREP * NB2;     // 24672 (fallback hist)
constexpr int HF_OFF    = LOW_OFF + NBKT;           // 28768 (reduced hist, NB2)
constexpr int ZERO_WORDS = LOW_OFF + NBKT;          // histF fully written by redR

__device__ __forceinline__ float sigmoidf_(float x) {
    return 1.0f / (1.0f + expf(-x));
}
__device__ __forceinline__ float softplusf_(float x) {
    return fmaxf(x, 0.0f) + log1pf(expf(-fabsf(x)));
}
__device__ __forceinline__ unsigned f2key(float x) {
    unsigned b = __float_as_uint(x);
    return b ^ ((unsigned)((int)b >> 31) | 0x80000000u);
}
__device__ __forceinline__ float key2f(unsigned k) {
    unsigned b = (k & 0x80000000u) ? (k & 0x7FFFFFFFu) : ~k;
    return __uint_as_float(b);
}

// 16 independent global_load_dwordx4, NO waitcnt (caller controls drain)
#define BURST16(P, T, pp, pp2, tp, tp2)                                      \
    asm volatile(                                                            \
        "global_load_dwordx4 %0, %16, off\n\t"                               \
        "global_load_dwordx4 %1, %16, off offset:1024\n\t"                   \
        "global_load_dwordx4 %2, %16, off offset:2048\n\t"                   \
        "global_load_dwordx4 %3, %16, off offset:3072\n\t"                   \
        "global_load_dwordx4 %4, %17, off\n\t"                               \
        "global_load_dwordx4 %5, %17, off offset:1024\n\t"                   \
        "global_load_dwordx4 %6, %17, off offset:2048\n\t"                   \
        "global_load_dwordx4 %7, %17, off offset:3072\n\t"                   \
        "global_load_dwordx4 %8, %18, off\n\t"                               \
        "global_load_dwordx4 %9, %18, off offset:1024\n\t"                   \
        "global_load_dwordx4 %10, %18, off offset:2048\n\t"                  \
        "global_load_dwordx4 %11, %18, off offset:3072\n\t"                  \
        "global_load_dwordx4 %12, %19, off\n\t"                              \
        "global_load_dwordx4 %13, %19, off offset:1024\n\t"                  \
        "global_load_dwordx4 %14, %19, off offset:2048\n\t"                  \
        "global_load_dwordx4 %15, %19, off offset:3072"                      \
        : "=&v"((P)[0]), "=&v"((P)[1]), "=&v"((P)[2]), "=&v"((P)[3]),        \
          "=&v"((P)[4]), "=&v"((P)[5]), "=&v"((P)[6]), "=&v"((P)[7]),        \
          "=&v"((T)[0]), "=&v"((T)[1]), "=&v"((T)[2]), "=&v"((T)[3]),        \
          "=&v"((T)[4]), "=&v"((T)[5]), "=&v"((T)[6]), "=&v"((T)[7])         \
        : "v"(pp), "v"(pp2), "v"(tp), "v"(tp2)                               \
        : "memory")

#define WAITVM(n) asm volatile("s_waitcnt vmcnt(" #n ")" ::: "memory")

// ---------------------------------------------------------------------------
__global__ void zeroAll(unsigned* ws, int nwords) {
    int stride = gridDim.x * blockDim.x;
    for (int i = blockIdx.x * blockDim.x + threadIdx.x; i < nwords; i += stride)
        ws[i] = 0u;
}

// K1: 4 tiles/block, ping-pong asm pipeline. Batch B's 16 loads are issued,
// then s_waitcnt vmcnt(16) waits only for batch A (FIFO) -> 16 KB/wave stays
// in flight DURING consume (round 11's burst drained to 0 before consuming).
__global__ __launch_bounds__(256) void k1(const float* __restrict__ preds,
                                          const int* __restrict__ targs, int N,
                                          float4* __restrict__ bstat,
                                          unsigned* __restrict__ rep) {
    __shared__ int lh[NB2];
    for (int i = threadIdx.x; i < NB2; i += 256) lh[i] = 0;
    __syncthreads();

    float pc = 0.f, psig = 0.f, plos = 0.f;
    const int tid = threadIdx.x;
    const int lane = tid & 63;
    const int w = tid >> 6;

    auto consume = [&](pf4 (&P)[8], pi4 (&T)[8]) {
#pragma unroll
        for (int g = 0; g < 8; g++) {
            pf4 pv = P[g]; pi4 tv = T[g];
#pragma unroll
            for (int j = 0; j < 4; j++) {
                float x = pv[j];
                unsigned key = f2key(x);
                if ((tv[j] == 0) && (key >= KEY15))
                    atomicAdd(&lh[(key >> 20) - BUCK0], 1);   // fire-and-forget ds_add
            }
            if (tv[0] | tv[1] | tv[2] | tv[3]) {   // rare positive path
#pragma unroll
                for (int j = 0; j < 4; j++)
                    if (tv[j]) {
                        float x = pv[j];
                        pc += 1.f; psig += sigmoidf_(x); plos += softplusf_(x) - x;
                    }
            }
        }
    };

    int nfull = N >> 13;                       // full 8192-element tiles
    int t0 = blockIdx.x * TPB;
    int tiles = nfull - t0; if (tiles > TPB) tiles = TPB;

    if (tiles > 0) {
        const size_t lbase = ((size_t)w << 11) + ((size_t)lane << 2);
        pf4 PA[8]; pi4 TA[8];
        pf4 PB[8]; pi4 TB[8];
        {
            size_t eb = ((size_t)t0 << 13) + lbase;
            BURST16(PA, TA, preds + eb, preds + eb + 1024, targs + eb, targs + eb + 1024);
        }
        int i = 0;
        while (true) {
            if (i + 1 < tiles) {
                size_t eb = ((size_t)(t0 + i + 1) << 13) + lbase;
                BURST16(PB, TB, preds + eb, preds + eb + 1024, targs + eb, targs + eb + 1024);
                WAITVM(16);
            } else WAITVM(0);
            consume(PA, TA);
            if (++i >= tiles) break;
            if (i + 1 < tiles) {
                size_t eb = ((size_t)(t0 + i + 1) << 13) + lbase;
                BURST16(PA, TA, preds + eb, preds + eb + 1024, targs + eb, targs + eb + 1024);
                WAITVM(16);
            } else WAITVM(0);
            consume(PB, TB);
            if (++i >= tiles) break;
        }
    }
    // tail elements (N % 8192), last block only
    if (blockIdx.x == gridDim.x - 1) {
        for (int i = (nfull << 13) + tid; i < N; i += 256) {
            float x = preds[i];
            if (targs[i]) { pc += 1.f; psig += sigmoidf_(x); plos += softplusf_(x) - x; }
            else {
                unsigned key = f2key(x);
                if (key >= KEY15) atomicAdd(&lh[(key >> 20) - BUCK0], 1);
            }
        }
    }
    __syncthreads();
    // flush hist + accumulate this block's qualifying count
    float qc = 0.f;
    unsigned* my = rep + (unsigned)(blockIdx.x & (NREP - 1)) * NB2;
    for (int i = tid; i < NB2; i += 256) {
        int c = lh[i];
        if (c) { atomicAdd(&my[i], (unsigned)c); qc += (float)c; }
    }
#pragma unroll
    for (int o = 32; o > 0; o >>= 1) {
        pc   += __shfl_down(pc, o);
        psig += __shfl_down(psig, o);
        plos += __shfl_down(plos, o);
        qc   += __shfl_down(qc, o);
    }
    __shared__ float rp[4], rs[4], rl[4], rq[4];
    if ((tid & 63) == 0) { rp[w] = pc; rs[w] = psig; rl[w] = plos; rq[w] = qc; }
    __syncthreads();
    if (tid == 0)
        bstat[blockIdx.x] = make_float4(rp[0] + rp[1] + rp[2] + rp[3],
                                        rs[0] + rs[1] + rs[2] + rs[3],
                                        rl[0] + rl[1] + rl[2] + rl[3],
                                        rq[0] + rq[1] + rq[2] + rq[3]);
}

// flagK: reduce per-block stats (qualifying count in .w) -> np, psig, plos,
// k, fallback flag.
__global__ void flagK(const float4* __restrict__ bstat, int nblocks,
                      unsigned* __restrict__ sc, unsigned N) {
    float pc = 0.f, ps = 0.f, pl = 0.f, qt = 0.f;
    for (int i = threadIdx.x; i < nblocks; i += 256) {
        float4 v = bstat[i];
        pc += v.x; ps += v.y; pl += v.z; qt += v.w;
    }
#pragma unroll
    for (int o = 32; o > 0; o >>= 1) {
        pc += __shfl_down(pc, o);
        ps += __shfl_down(ps, o);
        pl += __shfl_down(pl, o);
        qt += __shfl_down(qt, o);
    }
    __shared__ float rp[4], rs[4], rl[4], rq[4];
    int w = threadIdx.x >> 6;
    if ((threadIdx.x & 63) == 0) { rp[w] = pc; rs[w] = ps; rl[w] = pl; rq[w] = qt; }
    __syncthreads();
    if (threadIdx.x == 0) {
        unsigned np = (unsigned)(rp[0] + rp[1] + rp[2] + rp[3] + 0.5f);
        float psT = rs[0] + rs[1] + rs[2] + rs[3];
        float plT = rl[0] + rl[1] + rl[2] + rl[3];
        unsigned qtT = (unsigned)(rq[0] + rq[1] + rq[2] + rq[3] + 0.5f);
        unsigned nn = N - np;
        unsigned k = (np == 0u) ? (unsigned)(0.1 * (double)nn)
                                : ((30u * np < nn) ? 30u * np : nn);
        float* scf = (float*)sc;
        sc[0] = np; scf[1] = psT; scf[2] = plT; sc[3] = k;
        sc[7] = (k > qtT) ? 1u : 0u;
    }
}

// redR: multi-block replica reduction (round 12: finalize's single-block
// cross-XCD replica reads were the hidden ~40 us). 1 bucket/thread, 8
// independent loads in flight.
__global__ void redR(const unsigned* __restrict__ rep, unsigned* __restrict__ histF) {
    int i = blockIdx.x * 256 + threadIdx.x;
    if (i < NB2) {
        unsigned s0 = rep[0 * NB2 + i], s1 = rep[1 * NB2 + i];
        unsigned s2 = rep[2 * NB2 + i], s3 = rep[3 * NB2 + i];
        unsigned s4 = rep[4 * NB2 + i], s5 = rep[5 * NB2 + i];
        unsigned s6 = rep[6 * NB2 + i], s7 = rep[7 * NB2 + i];
        histF[i] = ((s0 + s1) + (s2 + s3)) + ((s4 + s5) + (s6 + s7));
    }
}

// Fallback (flag only): histogram negatives with key < KEY15. Normally exits.
__global__ __launch_bounds__(256) void lowH(const float* __restrict__ preds,
                                            const int* __restrict__ targs, int N,
                                            const unsigned* __restrict__ sc,
                                            unsigned* __restrict__ low) {
    if (sc[7] == 0u) return;
    int gtid = blockIdx.x * 256 + threadIdx.x;
    int gstr = gridDim.x * 256;
    for (int i = gtid; i < N; i += gstr) {
        if (!targs[i]) {
            unsigned key = f2key(preds[i]);
            if (key < KEY15) atomicAdd(&low[key >> 20], 1u);
        }
    }
}

// finalize: counts from pre-reduced histF (>= BUCK0) + low hist (< BUCK0,
// flag path) -- all loads independent; suffix-scan -> b1/r1; analytic
// bucket-midpoint sums; wave-shuffle reduction; dice + mean.
__global__ void finalize(const unsigned* __restrict__ histF,
                         const unsigned* __restrict__ low,
                         unsigned* __restrict__ sc, float* __restrict__ out) {
    __shared__ unsigned sa[256], sb[256];
    __shared__ int sb1;
    __shared__ unsigned sr1;
    __shared__ double rds[4], rdl[4];
    int t = threadIdx.x;
    int base = t * 16;
    unsigned c[16]; unsigned tot = 0;
#pragma unroll
    for (int j = 0; j < 16; j++) {
        int b = base + j;
        unsigned s = (b >= BUCK0) ? histF[b - BUCK0] : low[b];
        c[j] = s; tot += s;
    }
    sa[t] = tot;
    if (t == 0) { sb1 = NBKT; sr1 = 0u; }
    __syncthreads();
    unsigned k = sc[3];
    unsigned* src = sa; unsigned* dst = sb;
    for (int off = 1; off < 256; off <<= 1) {
        unsigned v = src[t] + ((t + off < 256) ? src[t + off] : 0u);
        dst[t] = v;
        __syncthreads();
        unsigned* tmp = src; src = dst; dst = tmp;
    }
    if (k > 0u) {
        unsigned above = src[t] - tot;
        if (above < k && above + tot >= k) {
            unsigned cum = above;
            for (int j = 15; j >= 0; j--) {
                unsigned cc = c[j];
                if (cum + cc >= k) { sb1 = base + j; sr1 = k - cum; break; }
                cum += cc;
            }
        }
    }
    __syncthreads();
    int b1 = sb1; unsigned r1 = sr1;
    double ssig = 0.0, ssp = 0.0;
#pragma unroll
    for (int j = 0; j < 16; j++) {
        int b = base + j; unsigned cc = c[j];
        if (cc == 0u) continue;
        bool full = (b > b1);
        bool part = (b == b1) && (r1 > 0u);
        if (!(full || part)) continue;
        float lo = key2f((unsigned)b << 20);
        float hi = (b == NBKT - 1) ? key2f(0xFF7FFFFFu)
                                   : key2f(((unsigned)(b + 1)) << 20);
        if (full) {
            float mid = 0.5f * (lo + hi);
            ssig += (double)cc * (double)sigmoidf_(mid);
            ssp  += (double)cc * (double)softplusf_(mid);
        } else {
            unsigned take = (r1 < cc) ? r1 : cc;
            double q = (double)take / (double)cc;
            float rp = (float)((double)hi - 0.5 * q * ((double)hi - (double)lo));
            ssig += (double)take * (double)sigmoidf_(rp);
            ssp  += (double)take * (double)softplusf_(rp);
        }
    }
#pragma unroll
    for (int o = 32; o > 0; o >>= 1) {
        ssig += __shfl_down(ssig, o);
        ssp  += __shfl_down(ssp, o);
    }
    int w = t >> 6;
    if ((t & 63) == 0) { rds[w] = ssig; rdl[w] = ssp; }
    __syncthreads();
    if (t == 0) {
        double sns = rds[0] + rds[1] + rds[2] + rds[3];
        double snl = rdl[0] + rdl[1] + rdl[2] + rdl[3];
        float* scf = (float*)sc;
        unsigned np = sc[0];
        float psig = scf[1], plos = scf[2];
        double denom = (double)psig + sns + (double)np;
        double dice = 1.0 - (2.0 * (double)psig + (double)EPSF) / (denom + (double)EPSF);
        unsigned totsel = np + k;
        double mean = totsel ? (((double)plos + snl) / (double)totsel) : 0.0;
        out[0] = (float)(dice + mean);
    }
}

// ---------------------------------------------------------------------------
extern "C" void kernel_launch(void* const* d_in, const int* in_sizes, int n_in,
                              void* d_out, int out_size, void* d_ws, size_t ws_size,
                              hipStream_t stream) {
    const float* preds = (const float*)d_in[0];
    const int*   targs = (const int*)d_in[1];
    float* out = (float*)d_out;
    int N = in_sizes[0];

    unsigned* ws    = (unsigned*)d_ws;
    unsigned* sc    = ws + SC_OFF;
    float4*   bstat = (float4*)(ws + BSTAT_OFF);
    unsigned* rep   = ws + REP_OFF;
    unsigned* low   = ws + LOW_OFF;
    unsigned* histF = ws + HF_OFF;

    int nfull = N >> 13;
    int grid = (nfull + TPB - 1) / TPB;
    if ((N & 8191) && grid * TPB <= nfull) grid++;   // ensure a block for tail
    if (grid < 1) grid = 1;
    if (grid > 4096) grid = 4096;                    // bstat bound

    zeroAll<<<64, 256, 0, stream>>>(ws, ZERO_WORDS);
    k1<<<grid, 256, 0, stream>>>(preds, targs, N, bstat, rep);
    flagK<<<1, 256, 0, stream>>>(bstat, grid, sc, (unsigned)N);
    lowH<<<512, 256, 0, stream>>>(preds, targs, N, sc, low);
    redR<<<(NB2 + 255) / 256, 256, 0, stream>>>(rep, histF);
    finalize<<<1, 256, 0, stream>>>(histF, low, sc, out);
}

// Round 14
// 164.462 us; speedup vs baseline: 1.2312x; 1.2312x over previous
//
#include <hip/hip_runtime.h>

#define EPSF 1e-10f

constexpr unsigned KEY15 = 0xBFC00000u;  // f2key(1.5f), bucket-aligned
constexpr int BUCK0 = 0xBFC;             // first tracked bucket (3068)
constexpr int NB2   = 4096 - BUCK0;      // 1028 tracked buckets
constexpr int NBKT  = 4096;
constexpr int NREP  = 8;                 // replica rows for flush

typedef float pf4 __attribute__((ext_vector_type(4)));
typedef int   pi4 __attribute__((ext_vector_type(4)));

// ---------- workspace layout (words) ----------
// sc: 0 np(u32) 1 psig(f32) 2 plos(f32) 3 k(u32) 7 flag(u32)
constexpr int SC_OFF    = 0;
constexpr int BSTAT_OFF = 64;                       // 4096 float4 (16384 words)
constexpr int REP_OFF   = BSTAT_OFF + 4096 * 4;     // 16448
constexpr int LOW_OFF   = REP_OFF + NREP * NB2;     // 24672 (fallback hist)
constexpr int HF_OFF    = LOW_OFF + NBKT;           // 28768 (reduced hist)
constexpr int ZERO_WORDS = LOW_OFF + NBKT;          // histF fully written by redR

__device__ __forceinline__ float sigmoidf_(float x) {
    return 1.0f / (1.0f + expf(-x));
}
__device__ __forceinline__ float softplusf_(float x) {
    return fmaxf(x, 0.0f) + log1pf(expf(-fabsf(x)));
}
__device__ __forceinline__ unsigned f2key(float x) {
    unsigned b = __float_as_uint(x);
    return b ^ ((unsigned)((int)b >> 31) | 0x80000000u);
}
__device__ __forceinline__ float key2f(unsigned k) {
    unsigned b = (k & 0x80000000u) ? (k & 0x7FFFFFFFu) : ~k;
    return __uint_as_float(b);
}

// ---------------------------------------------------------------------------
__global__ void zeroAll(unsigned* ws, int nwords) {
    int stride = gridDim.x * blockDim.x;
    for (int i = blockIdx.x * blockDim.x + threadIdx.x; i < nwords; i += stride)
        ws[i] = 0u;
}

// K1: round-12 verbatim (empirical optimum of the MLP/occupancy trade:
// 16-load asm burst + vmcnt(0), 1 tile/block, grid 2048, VGPR 48, 46-48 us.
// Round 13's 2-deep pipeline raised VGPR to 84 but dropped occupancy to 18%
// and regressed to 56 us).
__global__ __launch_bounds__(256) void k1(const float* __restrict__ preds,
                                          const int* __restrict__ targs, int N,
                                          float4* __restrict__ bstat,
                                          unsigned* __restrict__ rep) {
    __shared__ int lh[NB2];
    for (int i = threadIdx.x; i < NB2; i += 256) lh[i] = 0;
    __syncthreads();

    float pc = 0.f, psig = 0.f, plos = 0.f;
    const int tid = threadIdx.x;
    const int lane = tid & 63;
    const int w = tid >> 6;

    int nfull = N >> 13;                     // full 8192-element tiles
    for (int grp = blockIdx.x; grp < nfull; grp += gridDim.x) {
        size_t ebase = ((size_t)grp << 13) + ((size_t)w << 11) + ((size_t)lane << 2);
        const float* pp  = preds + ebase;        // wave tile: 2048 elements
        const float* pp2 = pp + 1024;
        const int*   tp  = targs + ebase;
        const int*   tp2 = tp + 1024;
        pf4 P[8]; pi4 T[8];
        asm volatile(
            "global_load_dwordx4 %0, %16, off\n\t"
            "global_load_dwordx4 %1, %16, off offset:1024\n\t"
            "global_load_dwordx4 %2, %16, off offset:2048\n\t"
            "global_load_dwordx4 %3, %16, off offset:3072\n\t"
            "global_load_dwordx4 %4, %17, off\n\t"
            "global_load_dwordx4 %5, %17, off offset:1024\n\t"
            "global_load_dwordx4 %6, %17, off offset:2048\n\t"
            "global_load_dwordx4 %7, %17, off offset:3072\n\t"
            "global_load_dwordx4 %8, %18, off\n\t"
            "global_load_dwordx4 %9, %18, off offset:1024\n\t"
            "global_load_dwordx4 %10, %18, off offset:2048\n\t"
            "global_load_dwordx4 %11, %18, off offset:3072\n\t"
            "global_load_dwordx4 %12, %19, off\n\t"
            "global_load_dwordx4 %13, %19, off offset:1024\n\t"
            "global_load_dwordx4 %14, %19, off offset:2048\n\t"
            "global_load_dwordx4 %15, %19, off offset:3072\n\t"
            "s_waitcnt vmcnt(0)"
            : "=&v"(P[0]), "=&v"(P[1]), "=&v"(P[2]), "=&v"(P[3]),
              "=&v"(P[4]), "=&v"(P[5]), "=&v"(P[6]), "=&v"(P[7]),
              "=&v"(T[0]), "=&v"(T[1]), "=&v"(T[2]), "=&v"(T[3]),
              "=&v"(T[4]), "=&v"(T[5]), "=&v"(T[6]), "=&v"(T[7])
            : "v"(pp), "v"(pp2), "v"(tp), "v"(tp2)
            : "memory");
#pragma unroll
        for (int g = 0; g < 8; g++) {
            pf4 pv = P[g]; pi4 tv = T[g];
#pragma unroll
            for (int j = 0; j < 4; j++) {
                float x = pv[j];
                unsigned key = f2key(x);
                if ((tv[j] == 0) && (key >= KEY15))
                    atomicAdd(&lh[(key >> 20) - BUCK0], 1);   // fire-and-forget ds_add
            }
            if (tv[0] | tv[1] | tv[2] | tv[3]) {   // rare positive path
#pragma unroll
                for (int j = 0; j < 4; j++)
                    if (tv[j]) {
                        float x = pv[j];
                        pc += 1.f; psig += sigmoidf_(x); plos += softplusf_(x) - x;
                    }
            }
        }
    }
    // tail elements (N % 8192), last block only
    if (blockIdx.x == gridDim.x - 1) {
        for (int i = (nfull << 13) + tid; i < N; i += 256) {
            float x = preds[i];
            if (targs[i]) { pc += 1.f; psig += sigmoidf_(x); plos += softplusf_(x) - x; }
            else {
                unsigned key = f2key(x);
                if (key >= KEY15) atomicAdd(&lh[(key >> 20) - BUCK0], 1);
            }
        }
    }
    __syncthreads();
    // flush hist + accumulate this block's qualifying count
    float qc = 0.f;
    unsigned* my = rep + (unsigned)(blockIdx.x & (NREP - 1)) * NB2;
    for (int i = tid; i < NB2; i += 256) {
        int c = lh[i];
        if (c) { atomicAdd(&my[i], (unsigned)c); qc += (float)c; }
    }
#pragma unroll
    for (int o = 32; o > 0; o >>= 1) {
        pc   += __shfl_down(pc, o);
        psig += __shfl_down(psig, o);
        plos += __shfl_down(plos, o);
        qc   += __shfl_down(qc, o);
    }
    __shared__ float rp[4], rs[4], rl[4], rq[4];
    if ((tid & 63) == 0) { rp[w] = pc; rs[w] = psig; rl[w] = plos; rq[w] = qc; }
    __syncthreads();
    if (tid == 0)
        bstat[blockIdx.x] = make_float4(rp[0] + rp[1] + rp[2] + rp[3],
                                        rs[0] + rs[1] + rs[2] + rs[3],
                                        rl[0] + rl[1] + rl[2] + rl[3],
                                        rq[0] + rq[1] + rq[2] + rq[3]);
}

// flagK: reduce per-block stats (qualifying count in .w) -> np, psig, plos,
// k, fallback flag.
__global__ void flagK(const float4* __restrict__ bstat, int nblocks,
                      unsigned* __restrict__ sc, unsigned N) {
    float pc = 0.f, ps = 0.f, pl = 0.f, qt = 0.f;
    for (int i = threadIdx.x; i < nblocks; i += 256) {
        float4 v = bstat[i];
        pc += v.x; ps += v.y; pl += v.z; qt += v.w;
    }
#pragma unroll
    for (int o = 32; o > 0; o >>= 1) {
        pc += __shfl_down(pc, o);
        ps += __shfl_down(ps, o);
        pl += __shfl_down(pl, o);
        qt += __shfl_down(qt, o);
    }
    __shared__ float rp[4], rs[4], rl[4], rq[4];
    int w = threadIdx.x >> 6;
    if ((threadIdx.x & 63) == 0) { rp[w] = pc; rs[w] = ps; rl[w] = pl; rq[w] = qt; }
    __syncthreads();
    if (threadIdx.x == 0) {
        unsigned np = (unsigned)(rp[0] + rp[1] + rp[2] + rp[3] + 0.5f);
        float psT = rs[0] + rs[1] + rs[2] + rs[3];
        float plT = rl[0] + rl[1] + rl[2] + rl[3];
        unsigned qtT = (unsigned)(rq[0] + rq[1] + rq[2] + rq[3] + 0.5f);
        unsigned nn = N - np;
        unsigned k = (np == 0u) ? (unsigned)(0.1 * (double)nn)
                                : ((30u * np < nn) ? 30u * np : nn);
        float* scf = (float*)sc;
        sc[0] = np; scf[1] = psT; scf[2] = plT; sc[3] = k;
        sc[7] = (k > qtT) ? 1u : 0u;
    }
}

// redR: multi-block replica reduction (keeps the cross-XCD latency-chained
// reads OUT of the single-block finalize). 8 independent loads per thread.
__global__ void redR(const unsigned* __restrict__ rep, unsigned* __restrict__ histF) {
    int i = blockIdx.x * 256 + threadIdx.x;
    if (i < NB2) {
        unsigned s0 = rep[0 * NB2 + i], s1 = rep[1 * NB2 + i];
        unsigned s2 = rep[2 * NB2 + i], s3 = rep[3 * NB2 + i];
        unsigned s4 = rep[4 * NB2 + i], s5 = rep[5 * NB2 + i];
        unsigned s6 = rep[6 * NB2 + i], s7 = rep[7 * NB2 + i];
        histF[i] = ((s0 + s1) + (s2 + s3)) + ((s4 + s5) + (s6 + s7));
    }
}

// Fallback (flag only): histogram negatives with key < KEY15. Normally exits.
__global__ __launch_bounds__(256) void lowH(const float* __restrict__ preds,
                                            const int* __restrict__ targs, int N,
                                            const unsigned* __restrict__ sc,
                                            unsigned* __restrict__ low) {
    if (sc[7] == 0u) return;
    int gtid = blockIdx.x * 256 + threadIdx.x;
    int gstr = gridDim.x * 256;
    for (int i = gtid; i < N; i += gstr) {
        if (!targs[i]) {
            unsigned key = f2key(preds[i]);
            if (key < KEY15) atomicAdd(&low[key >> 20], 1u);
        }
    }
}

// finalize: counts from pre-reduced histF (>= BUCK0) + low hist (< BUCK0,
// flag path) -- all loads independent; suffix-scan -> b1/r1; analytic
// bucket-midpoint sums; wave-shuffle reduction; dice + mean.
__global__ void finalize(const unsigned* __restrict__ histF,
                         const unsigned* __restrict__ low,
                         unsigned* __restrict__ sc, float* __restrict__ out) {
    __shared__ unsigned sa[256], sb[256];
    __shared__ int sb1;
    __shared__ unsigned sr1;
    __shared__ double rds[4], rdl[4];
    int t = threadIdx.x;
    int base = t * 16;
    unsigned c[16]; unsigned tot = 0;
#pragma unroll
    for (int j = 0; j < 16; j++) {
        int b = base + j;
        unsigned s = (b >= BUCK0) ? histF[b - BUCK0] : low[b];
        c[j] = s; tot += s;
    }
    sa[t] = tot;
    if (t == 0) { sb1 = NBKT; sr1 = 0u; }
    __syncthreads();
    unsigned k = sc[3];
    unsigned* src = sa; unsigned* dst = sb;
    for (int off = 1; off < 256; off <<= 1) {
        unsigned v = src[t] + ((t + off < 256) ? src[t + off] : 0u);
        dst[t] = v;
        __syncthreads();
        unsigned* tmp = src; src = dst; dst = tmp;
    }
    if (k > 0u) {
        unsigned above = src[t] - tot;
        if (above < k && above + tot >= k) {
            unsigned cum = above;
            for (int j = 15; j >= 0; j--) {
                unsigned cc = c[j];
                if (cum + cc >= k) { sb1 = base + j; sr1 = k - cum; break; }
                cum += cc;
            }
        }
    }
    __syncthreads();
    int b1 = sb1; unsigned r1 = sr1;
    double ssig = 0.0, ssp = 0.0;
#pragma unroll
    for (int j = 0; j < 16; j++) {
        int b = base + j; unsigned cc = c[j];
        if (cc == 0u) continue;
        bool full = (b > b1);
        bool part = (b == b1) && (r1 > 0u);
        if (!(full || part)) continue;
        float lo = key2f((unsigned)b << 20);
        float hi = (b == NBKT - 1) ? key2f(0xFF7FFFFFu)
                                   : key2f(((unsigned)(b + 1)) << 20);
        if (full) {
            float mid = 0.5f * (lo + hi);
            ssig += (double)cc * (double)sigmoidf_(mid);
            ssp  += (double)cc * (double)softplusf_(mid);
        } else {
            unsigned take = (r1 < cc) ? r1 : cc;
            double q = (double)take / (double)cc;
            float rp = (float)((double)hi - 0.5 * q * ((double)hi - (double)lo));
            ssig += (double)take * (double)sigmoidf_(rp);
            ssp  += (double)take * (double)softplusf_(rp);
        }
    }
#pragma unroll
    for (int o = 32; o > 0; o >>= 1) {
        ssig += __shfl_down(ssig, o);
        ssp  += __shfl_down(ssp, o);
    }
    int w = t >> 6;
    if ((t & 63) == 0) { rds[w] = ssig; rdl[w] = ssp; }
    __syncthreads();
    if (t == 0) {
        double sns = rds[0] + rds[1] + rds[2] + rds[3];
        double snl = rdl[0] + rdl[1] + rdl[2] + rdl[3];
        float* scf = (float*)sc;
        unsigned np = sc[0];
        float psig = scf[1], plos = scf[2];
        double denom = (double)psig + sns + (double)np;
        double dice = 1.0 - (2.0 * (double)psig + (double)EPSF) / (denom + (double)EPSF);
        unsigned totsel = np + k;
        double mean = totsel ? (((double)plos + snl) / (double)totsel) : 0.0;
        out[0] = (float)(dice + mean);
    }
}

// ---------------------------------------------------------------------------
extern "C" void kernel_launch(void* const* d_in, const int* in_sizes, int n_in,
                              void* d_out, int out_size, void* d_ws, size_t ws_size,
                              hipStream_t stream) {
    const float* preds = (const float*)d_in[0];
    const int*   targs = (const int*)d_in[1];
    float* out = (float*)d_out;
    int N = in_sizes[0];

    unsigned* ws    = (unsigned*)d_ws;
    unsigned* sc    = ws + SC_OFF;
    float4*   bstat = (float4*)(ws + BSTAT_OFF);
    unsigned* rep   = ws + REP_OFF;
    unsigned* low   = ws + LOW_OFF;
    unsigned* histF = ws + HF_OFF;

    int nfull = N >> 13;
    int grid = nfull + ((N & 8191) ? 1 : 0);
    if (grid < 1) grid = 1;
    if (grid > 4096) grid = 4096;   // bstat bound; blocks grid-stride past

    zeroAll<<<64, 256, 0, stream>>>(ws, ZERO_WORDS);
    k1<<<grid, 256, 0, stream>>>(preds, targs, N, bstat, rep);
    flagK<<<1, 256, 0, stream>>>(bstat, grid, sc, (unsigned)N);
    lowH<<<512, 256, 0, stream>>>(preds, targs, N, sc, low);
    redR<<<(NB2 + 255) / 256, 256, 0, stream>>>(rep, histF);
    finalize<<<1, 256, 0, stream>>>(histF, low, sc, out);
}

// Round 15
// 162.872 us; speedup vs baseline: 1.2432x; 1.0098x over previous
//
#include <hip/hip_runtime.h>

#define EPSF 1e-10f

constexpr unsigned KEY15 = 0xBFC00000u;  // f2key(1.5f), bucket-aligned
constexpr int BUCK0 = 0xBFC;             // first tracked bucket (3068)
constexpr int NB2   = 4096 - BUCK0;      // 1028 tracked buckets
constexpr int NBKT  = 4096;
constexpr int NREP  = 8;                 // replica rows for flush
constexpr int LHSZ  = NB2 + 64;          // + 64 per-lane dummy slots

typedef float pf4 __attribute__((ext_vector_type(4)));
typedef int   pi4 __attribute__((ext_vector_type(4)));

// ---------- workspace layout (words) ----------
// sc: 0 np(u32) 1 psig(f32) 2 plos(f32) 3 k(u32) 7 flag(u32)
constexpr int SC_OFF    = 0;
constexpr int BSTAT_OFF = 64;                       // 4096 float4 (16384 words)
constexpr int REP_OFF   = BSTAT_OFF + 4096 * 4;     // 16448
constexpr int LOW_OFF   = REP_OFF + NREP * NB2;     // 24672 (fallback hist)
constexpr int HF_OFF    = LOW_OFF + NBKT;           // 28768 (reduced hist)
constexpr int ZERO_WORDS = LOW_OFF + NBKT;          // histF fully written by redR

__device__ __forceinline__ float sigmoidf_(float x) {
    return 1.0f / (1.0f + expf(-x));
}
__device__ __forceinline__ float softplusf_(float x) {
    return fmaxf(x, 0.0f) + log1pf(expf(-fabsf(x)));
}
__device__ __forceinline__ unsigned f2key(float x) {
    unsigned b = __float_as_uint(x);
    return b ^ ((unsigned)((int)b >> 31) | 0x80000000u);
}
__device__ __forceinline__ float key2f(unsigned k) {
    unsigned b = (k & 0x80000000u) ? (k & 0x7FFFFFFFu) : ~k;
    return __uint_as_float(b);
}

// ---------------------------------------------------------------------------
__global__ void zeroAll(unsigned* ws, int nwords) {
    int stride = gridDim.x * blockDim.x;
    for (int i = blockIdx.x * blockDim.x + threadIdx.x; i < nwords; i += stride)
        ws[i] = 0u;
}

// K1: round-12/14 load structure (16-load asm burst + vmcnt(0) -- empirical
// optimum of MLP/occupancy), but BRANCHLESS consume: unconditional ds_add to
// cndmask-selected address (real bucket | per-lane dummy). Removes the
// per-element v_cmp/s_and_saveexec/ds/restore exec-churn that issued on ~88%
// of element-slots (round 14's cached replay at unchanged 46 us proved the
// kernel is issue-bound, not memory-bound). Per-lane dummies avoid round 4's
// 60-way same-address RMW serialization.
__global__ __launch_bounds__(256) void k1(const float* __restrict__ preds,
                                          const int* __restrict__ targs, int N,
                                          float4* __restrict__ bstat,
                                          unsigned* __restrict__ rep) {
    __shared__ int lh[LHSZ];
    for (int i = threadIdx.x; i < LHSZ; i += 256) lh[i] = 0;
    __syncthreads();

    float pc = 0.f, psig = 0.f, plos = 0.f;
    const int tid = threadIdx.x;
    const int lane = tid & 63;
    const int w = tid >> 6;
    const int dummy = NB2 + lane;            // per-lane dummy slot

    int nfull = N >> 13;                     // full 8192-element tiles
    for (int grp = blockIdx.x; grp < nfull; grp += gridDim.x) {
        size_t ebase = ((size_t)grp << 13) + ((size_t)w << 11) + ((size_t)lane << 2);
        const float* pp  = preds + ebase;        // wave tile: 2048 elements
        const float* pp2 = pp + 1024;
        const int*   tp  = targs + ebase;
        const int*   tp2 = tp + 1024;
        pf4 P[8]; pi4 T[8];
        asm volatile(
            "global_load_dwordx4 %0, %16, off\n\t"
            "global_load_dwordx4 %1, %16, off offset:1024\n\t"
            "global_load_dwordx4 %2, %16, off offset:2048\n\t"
            "global_load_dwordx4 %3, %16, off offset:3072\n\t"
            "global_load_dwordx4 %4, %17, off\n\t"
            "global_load_dwordx4 %5, %17, off offset:1024\n\t"
            "global_load_dwordx4 %6, %17, off offset:2048\n\t"
            "global_load_dwordx4 %7, %17, off offset:3072\n\t"
            "global_load_dwordx4 %8, %18, off\n\t"
            "global_load_dwordx4 %9, %18, off offset:1024\n\t"
            "global_load_dwordx4 %10, %18, off offset:2048\n\t"
            "global_load_dwordx4 %11, %18, off offset:3072\n\t"
            "global_load_dwordx4 %12, %19, off\n\t"
            "global_load_dwordx4 %13, %19, off offset:1024\n\t"
            "global_load_dwordx4 %14, %19, off offset:2048\n\t"
            "global_load_dwordx4 %15, %19, off offset:3072\n\t"
            "s_waitcnt vmcnt(0)"
            : "=&v"(P[0]), "=&v"(P[1]), "=&v"(P[2]), "=&v"(P[3]),
              "=&v"(P[4]), "=&v"(P[5]), "=&v"(P[6]), "=&v"(P[7]),
              "=&v"(T[0]), "=&v"(T[1]), "=&v"(T[2]), "=&v"(T[3]),
              "=&v"(T[4]), "=&v"(T[5]), "=&v"(T[6]), "=&v"(T[7])
            : "v"(pp), "v"(pp2), "v"(tp), "v"(tp2)
            : "memory");
#pragma unroll
        for (int g = 0; g < 8; g++) {
            pf4 pv = P[g]; pi4 tv = T[g];
#pragma unroll
            for (int j = 0; j < 4; j++) {
                float x = pv[j];
                unsigned key = f2key(x);
                int bkt = (int)(key >> 20) - BUCK0;
                bool q = (key >= KEY15) & (tv[j] == 0);
                int addr = q ? bkt : dummy;        // v_cndmask, no exec churn
                atomicAdd(&lh[addr], 1);           // unconditional ds_add
            }
            if (tv[0] | tv[1] | tv[2] | tv[3]) {   // rare positive path
#pragma unroll
                for (int j = 0; j < 4; j++)
                    if (tv[j]) {
                        float x = pv[j];
                        pc += 1.f; psig += sigmoidf_(x); plos += softplusf_(x) - x;
                    }
            }
        }
    }
    // tail elements (N % 8192), last block only
    if (blockIdx.x == gridDim.x - 1) {
        for (int i = (nfull << 13) + tid; i < N; i += 256) {
            float x = preds[i];
            if (targs[i]) { pc += 1.f; psig += sigmoidf_(x); plos += softplusf_(x) - x; }
            else {
                unsigned key = f2key(x);
                if (key >= KEY15) atomicAdd(&lh[(key >> 20) - BUCK0], 1);
            }
        }
    }
    __syncthreads();
    // flush hist (dummy slots >= NB2 ignored) + qualifying count
    float qc = 0.f;
    unsigned* my = rep + (unsigned)(blockIdx.x & (NREP - 1)) * NB2;
    for (int i = tid; i < NB2; i += 256) {
        int c = lh[i];
        if (c) { atomicAdd(&my[i], (unsigned)c); qc += (float)c; }
    }
#pragma unroll
    for (int o = 32; o > 0; o >>= 1) {
        pc   += __shfl_down(pc, o);
        psig += __shfl_down(psig, o);
        plos += __shfl_down(plos, o);
        qc   += __shfl_down(qc, o);
    }
    __shared__ float rp[4], rs[4], rl[4], rq[4];
    if ((tid & 63) == 0) { rp[w] = pc; rs[w] = psig; rl[w] = plos; rq[w] = qc; }
    __syncthreads();
    if (tid == 0)
        bstat[blockIdx.x] = make_float4(rp[0] + rp[1] + rp[2] + rp[3],
                                        rs[0] + rs[1] + rs[2] + rs[3],
                                        rl[0] + rl[1] + rl[2] + rl[3],
                                        rq[0] + rq[1] + rq[2] + rq[3]);
}

// flagK: reduce per-block stats (qualifying count in .w) -> np, psig, plos,
// k, fallback flag.
__global__ void flagK(const float4* __restrict__ bstat, int nblocks,
                      unsigned* __restrict__ sc, unsigned N) {
    float pc = 0.f, ps = 0.f, pl = 0.f, qt = 0.f;
    for (int i = threadIdx.x; i < nblocks; i += 256) {
        float4 v = bstat[i];
        pc += v.x; ps += v.y; pl += v.z; qt += v.w;
    }
#pragma unroll
    for (int o = 32; o > 0; o >>= 1) {
        pc += __shfl_down(pc, o);
        ps += __shfl_down(ps, o);
        pl += __shfl_down(pl, o);
        qt += __shfl_down(qt, o);
    }
    __shared__ float rp[4], rs[4], rl[4], rq[4];
    int w = threadIdx.x >> 6;
    if ((threadIdx.x & 63) == 0) { rp[w] = pc; rs[w] = ps; rl[w] = pl; rq[w] = qt; }
    __syncthreads();
    if (threadIdx.x == 0) {
        unsigned np = (unsigned)(rp[0] + rp[1] + rp[2] + rp[3] + 0.5f);
        float psT = rs[0] + rs[1] + rs[2] + rs[3];
        float plT = rl[0] + rl[1] + rl[2] + rl[3];
        unsigned qtT = (unsigned)(rq[0] + rq[1] + rq[2] + rq[3] + 0.5f);
        unsigned nn = N - np;
        unsigned k = (np == 0u) ? (unsigned)(0.1 * (double)nn)
                                : ((30u * np < nn) ? 30u * np : nn);
        float* scf = (float*)sc;
        sc[0] = np; scf[1] = psT; scf[2] = plT; sc[3] = k;
        sc[7] = (k > qtT) ? 1u : 0u;
    }
}

// redR: multi-block replica reduction (keeps cross-XCD latency-chained reads
// OUT of the single-block finalize). 8 independent loads per thread.
__global__ void redR(const unsigned* __restrict__ rep, unsigned* __restrict__ histF) {
    int i = blockIdx.x * 256 + threadIdx.x;
    if (i < NB2) {
        unsigned s0 = rep[0 * NB2 + i], s1 = rep[1 * NB2 + i];
        unsigned s2 = rep[2 * NB2 + i], s3 = rep[3 * NB2 + i];
        unsigned s4 = rep[4 * NB2 + i], s5 = rep[5 * NB2 + i];
        unsigned s6 = rep[6 * NB2 + i], s7 = rep[7 * NB2 + i];
        histF[i] = ((s0 + s1) + (s2 + s3)) + ((s4 + s5) + (s6 + s7));
    }
}

// Fallback (flag only): histogram negatives with key < KEY15. Normally exits.
__global__ __launch_bounds__(256) void lowH(const float* __restrict__ preds,
                                            const int* __restrict__ targs, int N,
                                            const unsigned* __restrict__ sc,
                                            unsigned* __restrict__ low) {
    if (sc[7] == 0u) return;
    int gtid = blockIdx.x * 256 + threadIdx.x;
    int gstr = gridDim.x * 256;
    for (int i = gtid; i < N; i += gstr) {
        if (!targs[i]) {
            unsigned key = f2key(preds[i]);
            if (key < KEY15) atomicAdd(&low[key >> 20], 1u);
        }
    }
}

// finalize: counts from pre-reduced histF (>= BUCK0) + low hist (< BUCK0,
// flag path); suffix-scan -> b1/r1; analytic bucket-midpoint sums;
// wave-shuffle reduction; dice + mean.
__global__ void finalize(const unsigned* __restrict__ histF,
                         const unsigned* __restrict__ low,
                         unsigned* __restrict__ sc, float* __restrict__ out) {
    __shared__ unsigned sa[256], sb[256];
    __shared__ int sb1;
    __shared__ unsigned sr1;
    __shared__ double rds[4], rdl[4];
    int t = threadIdx.x;
    int base = t * 16;
    unsigned c[16]; unsigned tot = 0;
#pragma unroll
    for (int j = 0; j < 16; j++) {
        int b = base + j;
        unsigned s = (b >= BUCK0) ? histF[b - BUCK0] : low[b];
        c[j] = s; tot += s;
    }
    sa[t] = tot;
    if (t == 0) { sb1 = NBKT; sr1 = 0u; }
    __syncthreads();
    unsigned k = sc[3];
    unsigned* src = sa; unsigned* dst = sb;
    for (int off = 1; off < 256; off <<= 1) {
        unsigned v = src[t] + ((t + off < 256) ? src[t + off] : 0u);
        dst[t] = v;
        __syncthreads();
        unsigned* tmp = src; src = dst; dst = tmp;
    }
    if (k > 0u) {
        unsigned above = src[t] - tot;
        if (above < k && above + tot >= k) {
            unsigned cum = above;
            for (int j = 15; j >= 0; j--) {
                unsigned cc = c[j];
                if (cum + cc >= k) { sb1 = base + j; sr1 = k - cum; break; }
                cum += cc;
            }
        }
    }
    __syncthreads();
    int b1 = sb1; unsigned r1 = sr1;
    double ssig = 0.0, ssp = 0.0;
#pragma unroll
    for (int j = 0; j < 16; j++) {
        int b = base + j; unsigned cc = c[j];
        if (cc == 0u) continue;
        bool full = (b > b1);
        bool part = (b == b1) && (r1 > 0u);
        if (!(full || part)) continue;
        float lo = key2f((unsigned)b << 20);
        float hi = (b == NBKT - 1) ? key2f(0xFF7FFFFFu)
                                   : key2f(((unsigned)(b + 1)) << 20);
        if (full) {
            float mid = 0.5f * (lo + hi);
            ssig += (double)cc * (double)sigmoidf_(mid);
            ssp  += (double)cc * (double)softplusf_(mid);
        } else {
            unsigned take = (r1 < cc) ? r1 : cc;
            double q = (double)take / (double)cc;
            float rp = (float)((double)hi - 0.5 * q * ((double)hi - (double)lo));
            ssig += (double)take * (double)sigmoidf_(rp);
            ssp  += (double)take * (double)softplusf_(rp);
        }
    }
#pragma unroll
    for (int o = 32; o > 0; o >>= 1) {
        ssig += __shfl_down(ssig, o);
        ssp  += __shfl_down(ssp, o);
    }
    int w = t >> 6;
    if ((t & 63) == 0) { rds[w] = ssig; rdl[w] = ssp; }
    __syncthreads();
    if (t == 0) {
        double sns = rds[0] + rds[1] + rds[2] + rds[3];
        double snl = rdl[0] + rdl[1] + rdl[2] + rdl[3];
        float* scf = (float*)sc;
        unsigned np = sc[0];
        float psig = scf[1], plos = scf[2];
        double denom = (double)psig + sns + (double)np;
        double dice = 1.0 - (2.0 * (double)psig + (double)EPSF) / (denom + (double)EPSF);
        unsigned totsel = np + k;
        double mean = totsel ? (((double)plos + snl) / (double)totsel) : 0.0;
        out[0] = (float)(dice + mean);
    }
}

// ---------------------------------------------------------------------------
extern "C" void kernel_launch(void* const* d_in, const int* in_sizes, int n_in,
                              void* d_out, int out_size, void* d_ws, size_t ws_size,
                              hipStream_t stream) {
    const float* preds = (const float*)d_in[0];
    const int*   targs = (const int*)d_in[1];
    float* out = (float*)d_out;
    int N = in_sizes[0];

    unsigned* ws    = (unsigned*)d_ws;
    unsigned* sc    = ws + SC_OFF;
    float4*   bstat = (float4*)(ws + BSTAT_OFF);
    unsigned* rep   = ws + REP_OFF;
    unsigned* low   = ws + LOW_OFF;
    unsigned* histF = ws + HF_OFF;

    int nfull = N >> 13;
    int grid = nfull + ((N & 8191) ? 1 : 0);
    if (grid < 1) grid = 1;
    if (grid > 4096) grid = 4096;   // bstat bound; blocks grid-stride past

    zeroAll<<<64, 256, 0, stream>>>(ws, ZERO_WORDS);
    k1<<<grid, 256, 0, stream>>>(preds, targs, N, bstat, rep);
    flagK<<<1, 256, 0, stream>>>(bstat, grid, sc, (unsigned)N);
    lowH<<<512, 256, 0, stream>>>(preds, targs, N, sc, low);
    redR<<<(NB2 + 255) / 256, 256, 0, stream>>>(rep, histF);
    finalize<<<1, 256, 0, stream>>>(histF, low, sc, out);
}